// Round 8
// baseline (1329.072 us; speedup 1.0000x reference)
//
#include <hip/hip_runtime.h>
#include <hip/hip_cooperative_groups.h>

namespace cg = cooperative_groups;

#define NB   8
#define NPT  2048
#define NF   128
#define CR   64
#define EPSI 1e-5

// ============================ kNN (top-16, 2-D, exact f32+FMA emulation of np/jax) ============================
// PROVEN (rounds 6/7): passes, ~105 us, VALU-issue-bound. FROZEN.
__global__ void __launch_bounds__(256) knn_kernel(const float* __restrict__ xyz,
                                                  int* __restrict__ idx16) {
  __shared__ float px[NPT], py[NPT], sxx[NPT];
  int b = blockIdx.x >> 9;
  const float* xb = xyz + b * 3 * NPT;
  for (int i = threadIdx.x; i < NPT; i += 256) {
    float x = xb[i], y = xb[NPT + i];
    px[i] = x; py[i] = y;
    sxx[i] = __fadd_rn(__fmul_rn(x, x), __fmul_rn(y, y));
  }
  __syncthreads();
  int lane = threadIdx.x & 63, wid = threadIdx.x >> 6;
  int q = ((blockIdx.x & 511) << 2) | wid;
  float qx = px[q], qy = py[q], qxx = sxx[q];
  float dc[32];
#pragma unroll 4
  for (int j = 0; j < 32; ++j) {
    int m = lane + (j << 6);
    float inner_s = __fmaf_rn(qy, py[m], __fmul_rn(qx, px[m]));
    dc[j] = __fadd_rn(__fsub_rn(qxx, __fmul_rn(2.0f, inner_s)), sxx[m]);
  }
  int keep = 0;
  for (int r = 0; r < 16; ++r) {
    float dmin = dc[0]; int jmin = 0;
#pragma unroll
    for (int j = 1; j < 32; ++j) {
      bool better = dc[j] < dmin;
      dmin = better ? dc[j] : dmin;
      jmin = better ? j : jmin;
    }
    float hd = dmin;
    int   hm = lane + (jmin << 6);
#pragma unroll
    for (int off = 1; off < 64; off <<= 1) {
      float od = __shfl_xor(hd, off);
      int   om = __shfl_xor(hm, off);
      bool take = (od < hd) || (od == hd && om < hm);
      hd = take ? od : hd;
      hm = take ? om : hm;
    }
    if (lane == r) keep = hm;
    bool own = (hm & 63) == lane;
    int jw = hm >> 6;
#pragma unroll
    for (int j = 0; j < 32; ++j)
      dc[j] = (own && j == jw) ? 1e38f : dc[j];
  }
  if (lane < 16) idx16[((b * NPT + q) << 4) + lane] = keep;
}

// ======================================================================================
//                       MEGA KERNEL (cooperative, 1024 blocks x 256)
// LDS plan (floats): [0..4160) wfT/wlT or sc/sh banks; [4160..5184) dred (512 f64);
//                    [5184..5440) vstage; [5440..5568) scg/shg for lap.
// ======================================================================================
struct MegaParams {
  const float *feat, *w1, *b1, *g1, *be1, *wf, *bf, *gg, *bg, *wl, *bl, *gl, *bel,
              *w2, *b2, *g2, *be2, *w3, *b3, *g3, *be3;
  const int* idx16;
  float *x1, *tpre, *hpre, *y2, *outp;
  double *st0, *stg, *stl, *st2, *st3;
};

template<int IC, int OC>
__device__ __forceinline__ void conv_phase(const float* __restrict__ in, const float* __restrict__ w,
                                           const float* __restrict__ bias, float* __restrict__ outp,
                                           double* __restrict__ stats, float* ldsf) {
  double* red = (double*)(ldsf + 4160);      // [4][8][2] doubles
  const int lane = threadIdx.x & 63, wid = threadIdx.x >> 6;
  for (int bz = blockIdx.x; bz < 8 * OC; bz += gridDim.x) {
    int n  = ((bz & 7) << 8) | threadIdx.x;
    int o0 = ((bz >> 3) % (OC / 8)) * 8;
    int b  = bz / (8 * (OC / 8));
    const float* inb = in + b * IC * NPT + n;
    float a[8];
#pragma unroll
    for (int t = 0; t < 8; ++t) a[t] = bias[o0 + t];
    const float* wb = w + o0 * IC;
#pragma unroll 4
    for (int f = 0; f < IC; ++f) {
      float v = inb[f * NPT];
#pragma unroll
      for (int t = 0; t < 8; ++t) a[t] += wb[t * IC + f] * v;
    }
    float* ob = outp + b * OC * NPT + n;
#pragma unroll
    for (int t = 0; t < 8; ++t) ob[(o0 + t) * NPT] = a[t];
#pragma unroll
    for (int j = 0; j < 8; ++j) {
      double s1 = (double)a[j];
      double s2 = (double)a[j] * (double)a[j];
#pragma unroll
      for (int off = 32; off; off >>= 1) { s1 += __shfl_down(s1, off); s2 += __shfl_down(s2, off); }
      if (lane == 0) { red[wid * 16 + j * 2] = s1; red[wid * 16 + j * 2 + 1] = s2; }
    }
    __syncthreads();
    if (threadIdx.x < 8) {
      int j = threadIdx.x;
      double S1 = red[j*2] + red[16 + j*2] + red[32 + j*2] + red[48 + j*2];
      double S2 = red[j*2+1] + red[16 + j*2+1] + red[32 + j*2+1] + red[48 + j*2+1];
      atomicAdd(&stats[o0 + j], S1);
      atomicAdd(&stats[OC + o0 + j], S2);
    }
    __syncthreads();
  }
}

template<int C>
__device__ __forceinline__ void bn_phase(const float* __restrict__ pre, const float* __restrict__ addsrc,
                                         float* __restrict__ outp, const double* __restrict__ stats,
                                         const float* __restrict__ gam, const float* __restrict__ bet,
                                         double inv_cnt, float* ldsf) {
  float* sc = ldsf; float* sh = ldsf + 256;
  for (int c = threadIdx.x; c < C; c += 256) {
    double mu    = stats[c] * inv_cnt;
    double var   = stats[C + c] * inv_cnt - mu * mu;
    double scale = (double)gam[c] / sqrt(var + EPSI);
    sc[c] = (float)scale;
    sh[c] = (float)((double)bet[c] - mu * scale);
  }
  __syncthreads();
  const float4* pre4 = (const float4*)pre;
  const float4* add4 = (const float4*)addsrc;
  float4* out4 = (float4*)outp;
  int total4 = NB * C * (NPT / 4);
  for (int i = blockIdx.x * 256 + threadIdx.x; i < total4; i += gridDim.x * 256) {
    int c = (i >> 9) & (C - 1);
    float s = sc[c], h = sh[c];
    float4 v = pre4[i];
    v.x = fmaxf(v.x * s + h, 0.f);
    v.y = fmaxf(v.y * s + h, 0.f);
    v.z = fmaxf(v.z * s + h, 0.f);
    v.w = fmaxf(v.w * s + h, 0.f);
    if (addsrc) {
      float4 a = add4[i];
      v.x += a.x; v.y += a.y; v.z += a.z; v.w += a.w;
    }
    out4[i] = v;
  }
}

__device__ __forceinline__ void dsgroup_phase(const float* __restrict__ x1, const int* __restrict__ idx16,
                                              const float* __restrict__ wf, const float* __restrict__ bfp,
                                              float* __restrict__ hmax, double* __restrict__ stats,
                                              float* ldsf) {
  float* wfT = ldsf;
  double* dred = (double*)(ldsf + 4160);     // [4][64][2]
  for (int i = threadIdx.x; i < 64 * 64; i += 256) {
    int o = i >> 6, f = i & 63;
    wfT[f * 65 + o] = wf[i];
  }
  __syncthreads();
  int lane = threadIdx.x & 63, wid = threadIdx.x >> 6;
  float bo = bfp[lane];
  double s1 = 0.0, s2 = 0.0;
  for (int vb = blockIdx.x; vb < 1024; vb += gridDim.x) {
    int wave = vb * 4 + wid;
    for (int p = 0; p < 4; ++p) {
      int pt = wave * 4 + p;
      int b = pt >> 11, n = pt & 2047;
      int src[8];
#pragma unroll
      for (int k = 0; k < 8; ++k) {
        int j = k * NPT + n;                 // torch-view scramble: idx[(j>>3), j&7]
        src[k] = idx16[((b * NPT + (j >> 3)) << 4) | (j & 7)];
      }
      float acc[8];
#pragma unroll
      for (int k = 0; k < 8; ++k) acc[k] = bo;
      const float* x1b = x1 + b * CR * NPT;
      for (int f = 0; f < 64; ++f) {
        float wv = wfT[f * 65 + lane];
        const float* row = x1b + f * NPT;
#pragma unroll
        for (int k = 0; k < 8; ++k) acc[k] += row[src[k]] * wv;
      }
      float hm = acc[0];
#pragma unroll
      for (int k = 0; k < 8; ++k) {
        hm = fmaxf(hm, acc[k]);
        s1 += (double)acc[k];
        s2 += (double)acc[k] * (double)acc[k];
      }
      hmax[(b * CR + lane) * NPT + n] = hm;  // max commutes with BN+ReLU (gamma>0)
    }
  }
  dred[wid * 128 + lane * 2] = s1; dred[wid * 128 + lane * 2 + 1] = s2;
  __syncthreads();
  if (threadIdx.x < 64) {
    int c = threadIdx.x;
    double S1 = dred[c*2] + dred[128 + c*2] + dred[256 + c*2] + dred[384 + c*2];
    double S2 = dred[c*2+1] + dred[128 + c*2+1] + dred[256 + c*2+1] + dred[384 + c*2+1];
    atomicAdd(&stats[c], S1);
    atomicAdd(&stats[64 + c], S2);
  }
  __syncthreads();
}

__device__ __forceinline__ void lap_phase(const float* __restrict__ hpre, const int* __restrict__ idx16,
                                          const float* __restrict__ wl, const float* __restrict__ blp,
                                          float* __restrict__ tpre, double* __restrict__ stats,
                                          const double* __restrict__ stg, const float* __restrict__ gg,
                                          const float* __restrict__ bg, float* ldsf) {
  float* wlT = ldsf;
  double* dred = (double*)(ldsf + 4160);
  float* vst0 = ldsf + 5184;                 // [4][64]
  float* scg  = ldsf + 5440;
  float* shg  = ldsf + 5504;
  for (int i = threadIdx.x; i < 64 * 64; i += 256) {
    int o = i >> 6, f = i & 63;
    wlT[f * 65 + o] = wl[i];
  }
  for (int c = threadIdx.x; c < 64; c += 256) {
    double mu    = stg[c] / 131072.0;
    double var   = stg[64 + c] / 131072.0 - mu * mu;
    double scale = (double)gg[c] / sqrt(var + EPSI);
    scg[c] = (float)scale;
    shg[c] = (float)((double)bg[c] - mu * scale);
  }
  __syncthreads();
  int lane = threadIdx.x & 63, wid = threadIdx.x >> 6;
  int g = lane >> 4, cc = lane & 15;
  float blv = blp[lane];
  float* vst = vst0 + wid * 64;
  double s1 = 0.0, s2 = 0.0;
  for (int vb = blockIdx.x; vb < 1024; vb += gridDim.x) {
    int wave = vb * 4 + wid;
    for (int p = 0; p < 4; ++p) {
      int pt = wave * 4 + p;
      int b = pt >> 11, n = pt & 2047;
      int ch = n >> 5;                       // gathered CHANNEL is n>>5 (torch-view scramble)
      int r0 = (n & 31) << 6;
      const float* xrow = hpre + (b * CR + ch) * NPT;
      const int* ib = idx16 + ((b * NPT + r0) << 4);
      float sgc = scg[ch], shc = shg[ch];
      float msum = 0.f;
#pragma unroll
      for (int kk = 0; kk < 16; ++kk) {
        int sidx = ib[(((kk << 2) + g) << 4) | cc];
        msum += fmaxf(fmaf(xrow[sidx], sgc, shc), 0.f);   // BN_g inline
      }
      float mval = msum * 0.0625f;
      float xraw = hpre[(b * CR + lane) * NPT + n];
      float xv = fmaxf(fmaf(xraw, scg[lane], shg[lane]), 0.f);
      vst[lane] = xv - mval;                 // wave-local staging
      float acc = blv;
      for (int f = 0; f < 64; ++f)
        acc += wlT[f * 65 + lane] * vst[f];
      tpre[(b * CR + lane) * NPT + n] = acc;
      s1 += (double)acc;
      s2 += (double)acc * (double)acc;
    }
  }
  dred[wid * 128 + lane * 2] = s1; dred[wid * 128 + lane * 2 + 1] = s2;
  __syncthreads();
  if (threadIdx.x < 64) {
    int c = threadIdx.x;
    double S1 = dred[c*2] + dred[128 + c*2] + dred[256 + c*2] + dred[384 + c*2];
    double S2 = dred[c*2+1] + dred[128 + c*2+1] + dred[256 + c*2+1] + dred[384 + c*2+1];
    atomicAdd(&stats[c], S1);
    atomicAdd(&stats[64 + c], S2);
  }
  __syncthreads();
}

__device__ __forceinline__ void combine_phase(float* __restrict__ hpre, const float* __restrict__ tpre,
                                              const double* __restrict__ stg, const float* __restrict__ gg,
                                              const float* __restrict__ bg, const double* __restrict__ stl,
                                              const float* __restrict__ gl, const float* __restrict__ bel,
                                              float* ldsf) {
  float* scg = ldsf; float* shg = ldsf + 256; float* scl = ldsf + 512; float* shl = ldsf + 768;
  for (int c = threadIdx.x; c < 64; c += 256) {
    double mu  = stg[c] / 131072.0;
    double var = stg[64 + c] / 131072.0 - mu * mu;
    double s   = (double)gg[c] / sqrt(var + EPSI);
    scg[c] = (float)s; shg[c] = (float)((double)bg[c] - mu * s);
    double mu2  = stl[c] / 16384.0;
    double var2 = stl[64 + c] / 16384.0 - mu2 * mu2;
    double s2   = (double)gl[c] / sqrt(var2 + EPSI);
    scl[c] = (float)s2; shl[c] = (float)((double)bel[c] - mu2 * s2);
  }
  __syncthreads();
  float4* h4 = (float4*)hpre;
  const float4* t4 = (const float4*)tpre;
  int total4 = NB * CR * (NPT / 4);
  for (int i = blockIdx.x * 256 + threadIdx.x; i < total4; i += gridDim.x * 256) {
    int c = (i >> 9) & 63;
    float sg = scg[c], hg = shg[c], sl = scl[c], hl = shl[c];
    float4 h = h4[i];
    float4 t = t4[i];
    h.x = fmaxf(h.x * sg + hg, 0.f) + fmaxf(t.x * sl + hl, 0.f);
    h.y = fmaxf(h.y * sg + hg, 0.f) + fmaxf(t.y * sl + hl, 0.f);
    h.z = fmaxf(h.z * sg + hg, 0.f) + fmaxf(t.z * sl + hl, 0.f);
    h.w = fmaxf(h.w * sg + hg, 0.f) + fmaxf(t.w * sl + hl, 0.f);
    h4[i] = h;
  }
}

__global__ void __launch_bounds__(256, 4) mega_kernel(MegaParams P) {
  cg::grid_group grid = cg::this_grid();
  __shared__ float ldsf[5952];
  conv_phase<128, 64>(P.feat, P.w1, P.b1, P.x1, P.st0, ldsf);               // mlp1 conv + stats
  grid.sync();
  bn_phase<64>(P.x1, nullptr, P.x1, P.st0, P.g1, P.be1, 1.0/16384.0, ldsf); // x1 = relu(bn1)
  grid.sync();
  dsgroup_phase(P.x1, P.idx16, P.wf, P.bf, P.hpre, P.stg, ldsf);            // hpre + stats_g
  grid.sync();
  lap_phase(P.hpre, P.idx16, P.wl, P.bl, P.tpre, P.stl, P.stg, P.gg, P.bg, ldsf); // tpre + stats_l (BN_g inline)
  grid.sync();
  combine_phase(P.hpre, P.tpre, P.stg, P.gg, P.bg, P.stl, P.gl, P.bel, ldsf); // x3 = relu(bn_g)+relu(bn_l), in hpre
  grid.sync();
  conv_phase<64, 128>(P.hpre, P.w2, P.b2, P.y2, P.st2, ldsf);               // mlp2 conv + stats
  grid.sync();
  bn_phase<128>(P.y2, P.feat, P.y2, P.st2, P.g2, P.be2, 1.0/16384.0, ldsf); // y2 = relu(bn2)+feat
  grid.sync();
  conv_phase<128, 256>(P.y2, P.w3, P.b3, P.outp, P.st3, ldsf);              // mlp3 conv + stats
  grid.sync();
  bn_phase<256>(P.outp, nullptr, P.outp, P.st3, P.g3, P.be3, 1.0/16384.0, ldsf); // out = relu(bn3)
}

// ============================ FALLBACK kernels (round-7 proven) ============================
template<int IC, int OC>
__global__ void __launch_bounds__(256) conv_stats(const float* __restrict__ in, const float* __restrict__ w,
                                                  const float* __restrict__ bias, float* __restrict__ outp,
                                                  double* __restrict__ stats) {
  int bz = blockIdx.x;
  int n  = ((bz & 7) << 8) | threadIdx.x;
  int o0 = ((bz >> 3) % (OC / 8)) * 8;
  int b  = bz / (8 * (OC / 8));
  const float* inb = in + b * IC * NPT + n;
  float a[8];
#pragma unroll
  for (int t = 0; t < 8; ++t) a[t] = bias[o0 + t];
  const float* wb = w + o0 * IC;
#pragma unroll 4
  for (int f = 0; f < IC; ++f) {
    float v = inb[f * NPT];
#pragma unroll
    for (int t = 0; t < 8; ++t) a[t] += wb[t * IC + f] * v;
  }
  float* ob = outp + b * OC * NPT + n;
#pragma unroll
  for (int t = 0; t < 8; ++t) ob[(o0 + t) * NPT] = a[t];
  __shared__ double red[4][8][2];
  int lane = threadIdx.x & 63, wid = threadIdx.x >> 6;
#pragma unroll
  for (int j = 0; j < 8; ++j) {
    double s1 = (double)a[j];
    double s2 = (double)a[j] * (double)a[j];
#pragma unroll
    for (int off = 32; off; off >>= 1) { s1 += __shfl_down(s1, off); s2 += __shfl_down(s2, off); }
    if (lane == 0) { red[wid][j][0] = s1; red[wid][j][1] = s2; }
  }
  __syncthreads();
  if (threadIdx.x < 8) {
    int j = threadIdx.x;
    double S1 = red[0][j][0] + red[1][j][0] + red[2][j][0] + red[3][j][0];
    double S2 = red[0][j][1] + red[1][j][1] + red[2][j][1] + red[3][j][1];
    atomicAdd(&stats[o0 + j], S1);
    atomicAdd(&stats[OC + o0 + j], S2);
  }
}

template<int C>
__global__ void __launch_bounds__(256) bn_apply(const float* __restrict__ pre, const float* __restrict__ addsrc,
                                                float* __restrict__ outp, const double* __restrict__ stats,
                                                const float* __restrict__ gam, const float* __restrict__ bet,
                                                double inv_cnt) {
  __shared__ float sc[C], sh[C];
  for (int c = threadIdx.x; c < C; c += 256) {
    double mu    = stats[c] * inv_cnt;
    double var   = stats[C + c] * inv_cnt - mu * mu;
    double scale = (double)gam[c] / sqrt(var + EPSI);
    sc[c] = (float)scale;
    sh[c] = (float)((double)bet[c] - mu * scale);
  }
  __syncthreads();
  const float4* pre4 = (const float4*)pre;
  const float4* add4 = (const float4*)addsrc;
  float4* out4 = (float4*)outp;
  int total4 = NB * C * (NPT / 4);
  for (int i = blockIdx.x * 256 + threadIdx.x; i < total4; i += gridDim.x * 256) {
    int c = (i >> 9) & (C - 1);
    float s = sc[c], h = sh[c];
    float4 v = pre4[i];
    v.x = fmaxf(v.x * s + h, 0.f);
    v.y = fmaxf(v.y * s + h, 0.f);
    v.z = fmaxf(v.z * s + h, 0.f);
    v.w = fmaxf(v.w * s + h, 0.f);
    if (addsrc) {
      float4 a = add4[i];
      v.x += a.x; v.y += a.y; v.z += a.z; v.w += a.w;
    }
    out4[i] = v;
  }
}

__global__ void __launch_bounds__(256) dsgroup_kernel(const float* __restrict__ x1, const int* __restrict__ idx16,
                                                      const float* __restrict__ wf, const float* __restrict__ bfp,
                                                      float* __restrict__ hmax, double* __restrict__ stats) {
  __shared__ float wfT[64 * 65];
  __shared__ double dred[4][64][2];
  for (int i = threadIdx.x; i < 64 * 64; i += 256) {
    int o = i >> 6, f = i & 63;
    wfT[f * 65 + o] = wf[i];
  }
  __syncthreads();
  int lane = threadIdx.x & 63, wid = threadIdx.x >> 6;
  int wave = blockIdx.x * 4 + wid;
  float bo = bfp[lane];
  double s1 = 0.0, s2 = 0.0;
  for (int p = 0; p < 4; ++p) {
    int pt = wave * 4 + p;
    int b = pt >> 11, n = pt & 2047;
    int src[8];
#pragma unroll
    for (int k = 0; k < 8; ++k) {
      int j = k * NPT + n;
      src[k] = idx16[((b * NPT + (j >> 3)) << 4) | (j & 7)];
    }
    float acc[8];
#pragma unroll
    for (int k = 0; k < 8; ++k) acc[k] = bo;
    const float* x1b = x1 + b * CR * NPT;
    for (int f = 0; f < 64; ++f) {
      float wv = wfT[f * 65 + lane];
      const float* row = x1b + f * NPT;
#pragma unroll
      for (int k = 0; k < 8; ++k) acc[k] += row[src[k]] * wv;
    }
    float hm = acc[0];
#pragma unroll
    for (int k = 0; k < 8; ++k) {
      hm = fmaxf(hm, acc[k]);
      s1 += (double)acc[k];
      s2 += (double)acc[k] * (double)acc[k];
    }
    hmax[(b * CR + lane) * NPT + n] = hm;
  }
  dred[wid][lane][0] = s1; dred[wid][lane][1] = s2;
  __syncthreads();
  if (threadIdx.x < 64) {
    double S1 = dred[0][threadIdx.x][0] + dred[1][threadIdx.x][0] + dred[2][threadIdx.x][0] + dred[3][threadIdx.x][0];
    double S2 = dred[0][threadIdx.x][1] + dred[1][threadIdx.x][1] + dred[2][threadIdx.x][1] + dred[3][threadIdx.x][1];
    atomicAdd(&stats[threadIdx.x], S1);
    atomicAdd(&stats[64 + threadIdx.x], S2);
  }
}

__global__ void __launch_bounds__(256) lap_kernel(const float* __restrict__ x2, const int* __restrict__ idx16,
                                                  const float* __restrict__ wl, const float* __restrict__ blp,
                                                  float* __restrict__ tpre, double* __restrict__ stats) {
  __shared__ float wlT[64 * 65];
  __shared__ double dred[4][64][2];
  __shared__ float vstage[4][64];
  for (int i = threadIdx.x; i < 64 * 64; i += 256) {
    int o = i >> 6, f = i & 63;
    wlT[f * 65 + o] = wl[i];
  }
  __syncthreads();
  int lane = threadIdx.x & 63, wid = threadIdx.x >> 6;
  int wave = blockIdx.x * 4 + wid;
  int g = lane >> 4, cc = lane & 15;
  float blv = blp[lane];
  double s1 = 0.0, s2 = 0.0;
  for (int p = 0; p < 4; ++p) {
    int pt = wave * 4 + p;
    int b = pt >> 11, n = pt & 2047;
    int ch = n >> 5;
    int r0 = (n & 31) << 6;
    const float* xrow = x2 + (b * CR + ch) * NPT;
    const int* ib = idx16 + ((b * NPT + r0) << 4);
    float msum = 0.f;
#pragma unroll
    for (int kk = 0; kk < 16; ++kk) {
      int sidx = ib[(((kk << 2) + g) << 4) | cc];
      msum += xrow[sidx];
    }
    float mval = msum * 0.0625f;
    float xv = x2[(b * CR + lane) * NPT + n];
    vstage[wid][lane] = xv - mval;
    float acc = blv;
    for (int f = 0; f < 64; ++f)
      acc += wlT[f * 65 + lane] * vstage[wid][f];
    tpre[(b * CR + lane) * NPT + n] = acc;
    s1 += (double)acc;
    s2 += (double)acc * (double)acc;
  }
  dred[wid][lane][0] = s1; dred[wid][lane][1] = s2;
  __syncthreads();
  if (threadIdx.x < 64) {
    double S1 = dred[0][threadIdx.x][0] + dred[1][threadIdx.x][0] + dred[2][threadIdx.x][0] + dred[3][threadIdx.x][0];
    double S2 = dred[0][threadIdx.x][1] + dred[1][threadIdx.x][1] + dred[2][threadIdx.x][1] + dred[3][threadIdx.x][1];
    atomicAdd(&stats[threadIdx.x], S1);
    atomicAdd(&stats[64 + threadIdx.x], S2);
  }
}

// ============================ launch ============================
extern "C" void kernel_launch(void* const* d_in, const int* in_sizes, int n_in,
                              void* d_out, int out_size, void* d_ws, size_t ws_size,
                              hipStream_t stream) {
  const float* xyz  = (const float*)d_in[0];
  const float* feat = (const float*)d_in[1];
  const float* w1   = (const float*)d_in[2];
  const float* b1   = (const float*)d_in[3];
  const float* g1   = (const float*)d_in[4];
  const float* be1  = (const float*)d_in[5];
  const float* wf   = (const float*)d_in[6];
  const float* bf   = (const float*)d_in[7];
  const float* gg   = (const float*)d_in[8];
  const float* bg   = (const float*)d_in[9];
  const float* wl   = (const float*)d_in[10];
  const float* bl   = (const float*)d_in[11];
  const float* gl   = (const float*)d_in[12];
  const float* bel  = (const float*)d_in[13];
  const float* w2   = (const float*)d_in[14];
  const float* b2   = (const float*)d_in[15];
  const float* g2   = (const float*)d_in[16];
  const float* be2  = (const float*)d_in[17];
  const float* w3   = (const float*)d_in[18];
  const float* b3   = (const float*)d_in[19];
  const float* g3   = (const float*)d_in[20];
  const float* be3  = (const float*)d_in[21];
  float* out = (float*)d_out;

  float* x1   = out;                       // [B][64][N] 4MB (dead by mlp3)
  float* tpre = out + 1048576;             // 4MB (dead by mlp3)
  int*  idx16 = (int*)(out + 2097152);     // 1MB (dead by mlp3)
  float*  hpre  = (float*)d_ws;            // 4MB: hpre -> x3 in place
  float*  y2    = hpre + 1048576;          // 8MB
  double* stats = (double*)((char*)d_ws + (12u << 20));
  double* st0 = stats;
  double* stg = stats + 128;
  double* stl = stats + 256;
  double* st2 = stats + 384;
  double* st3 = stats + 640;

  hipMemsetAsync(stats, 0, 1152 * sizeof(double), stream);

  knn_kernel<<<4096, 256, 0, stream>>>(xyz, idx16);

  MegaParams mp;
  mp.feat = feat; mp.w1 = w1; mp.b1 = b1; mp.g1 = g1; mp.be1 = be1;
  mp.wf = wf; mp.bf = bf; mp.gg = gg; mp.bg = bg;
  mp.wl = wl; mp.bl = bl; mp.gl = gl; mp.bel = bel;
  mp.w2 = w2; mp.b2 = b2; mp.g2 = g2; mp.be2 = be2;
  mp.w3 = w3; mp.b3 = b3; mp.g3 = g3; mp.be3 = be3;
  mp.idx16 = idx16;
  mp.x1 = x1; mp.tpre = tpre; mp.hpre = hpre; mp.y2 = y2; mp.outp = out;
  mp.st0 = st0; mp.stg = stg; mp.stl = stl; mp.st2 = st2; mp.st3 = st3;
  void* kp[] = { &mp };
  hipError_t e = hipLaunchCooperativeKernel((const void*)mega_kernel,
                                            dim3(1024), dim3(256), kp, 0, stream);
  if (e != hipSuccess) {
    // -------- fallback: round-7 proven multi-launch path --------
    conv_stats<128, 64><<<NB * 8 * 8, 256, 0, stream>>>(feat, w1, b1, x1, st0);
    bn_apply<64><<<1024, 256, 0, stream>>>(x1, nullptr, x1, st0, g1, be1, 1.0 / 16384.0);
    dsgroup_kernel<<<1024, 256, 0, stream>>>(x1, idx16, wf, bf, hpre, stg);
    bn_apply<64><<<1024, 256, 0, stream>>>(hpre, nullptr, hpre, stg, gg, bg, 1.0 / 131072.0);
    lap_kernel<<<1024, 256, 0, stream>>>(hpre, idx16, wl, bl, tpre, stl);
    bn_apply<64><<<1024, 256, 0, stream>>>(tpre, hpre, hpre, stl, gl, bel, 1.0 / 16384.0);
    conv_stats<64, 128><<<NB * 16 * 8, 256, 0, stream>>>(hpre, w2, b2, y2, st2);
    bn_apply<128><<<1024, 256, 0, stream>>>(y2, feat, y2, st2, g2, be2, 1.0 / 16384.0);
    conv_stats<128, 256><<<NB * 32 * 8, 256, 0, stream>>>(y2, w3, b3, out, st3);
    bn_apply<256><<<1024, 256, 0, stream>>>(out, nullptr, out, st3, g3, be3, 1.0 / 16384.0);
  }
}

// Round 11
// 300.981 us; speedup vs baseline: 4.4158x; 4.4158x over previous
//
#include <hip/hip_runtime.h>

#define NB   8
#define NPT  2048
#define NF   128
#define CR   64
#define EPSI 1e-5

// ============================ kNN (top-16, 2-D, exact f32+FMA emulation of np/jax) ============================
// PROVEN (rounds 6/7): passes, ~105 us, VALU-issue-bound. FROZEN — separate dispatch, own __shared__ arrays.
__global__ void __launch_bounds__(256) knn_kernel(const float* __restrict__ xyz,
                                                  int* __restrict__ idx16) {
  __shared__ float px[NPT], py[NPT], sxx[NPT];
  int b = blockIdx.x >> 9;
  const float* xb = xyz + b * 3 * NPT;
  for (int i = threadIdx.x; i < NPT; i += 256) {
    float x = xb[i], y = xb[NPT + i];
    px[i] = x; py[i] = y;
    sxx[i] = __fadd_rn(__fmul_rn(x, x), __fmul_rn(y, y));
  }
  __syncthreads();
  int lane = threadIdx.x & 63, wid = threadIdx.x >> 6;
  int q = ((blockIdx.x & 511) << 2) | wid;
  float qx = px[q], qy = py[q], qxx = sxx[q];
  float dc[32];
#pragma unroll 4
  for (int j = 0; j < 32; ++j) {
    int m = lane + (j << 6);
    float inner_s = __fmaf_rn(qy, py[m], __fmul_rn(qx, px[m]));
    dc[j] = __fadd_rn(__fsub_rn(qxx, __fmul_rn(2.0f, inner_s)), sxx[m]);
  }
  int keep = 0;
  for (int r = 0; r < 16; ++r) {
    float dmin = dc[0]; int jmin = 0;
#pragma unroll
    for (int j = 1; j < 32; ++j) {
      bool better = dc[j] < dmin;
      dmin = better ? dc[j] : dmin;
      jmin = better ? j : jmin;
    }
    float hd = dmin;
    int   hm = lane + (jmin << 6);
#pragma unroll
    for (int off = 1; off < 64; off <<= 1) {
      float od = __shfl_xor(hd, off);
      int   om = __shfl_xor(hm, off);
      bool take = (od < hd) || (od == hd && om < hm);
      hd = take ? od : hd;
      hm = take ? om : hm;
    }
    if (lane == r) keep = hm;
    bool own = (hm & 63) == lane;
    int jw = hm >> 6;
#pragma unroll
    for (int j = 0; j < 32; ++j)
      dc[j] = (own && j == jw) ? 1e38f : dc[j];
  }
  if (lane < 16) idx16[((b * NPT + q) << 4) + lane] = keep;
}

// ===================== generic conv + atomic stats (round-7 proven) =====================
template<int IC, int OC>
__global__ void __launch_bounds__(256) conv_stats(const float* __restrict__ in,
                                                  const float* __restrict__ w,
                                                  const float* __restrict__ bias,
                                                  float* __restrict__ outp,
                                                  double* __restrict__ stats) {
  int bz = blockIdx.x;
  int n  = ((bz & 7) << 8) | threadIdx.x;
  int o0 = ((bz >> 3) % (OC / 8)) * 8;
  int b  = bz / (8 * (OC / 8));
  const float* inb = in + b * IC * NPT + n;
  float a[8];
#pragma unroll
  for (int t = 0; t < 8; ++t) a[t] = bias[o0 + t];
  const float* wb = w + o0 * IC;
#pragma unroll 4
  for (int f = 0; f < IC; ++f) {
    float v = inb[f * NPT];
#pragma unroll
    for (int t = 0; t < 8; ++t) a[t] += wb[t * IC + f] * v;
  }
  float* ob = outp + b * OC * NPT + n;
#pragma unroll
  for (int t = 0; t < 8; ++t) ob[(o0 + t) * NPT] = a[t];
  __shared__ double red[4][8][2];
  int lane = threadIdx.x & 63, wid = threadIdx.x >> 6;
#pragma unroll
  for (int j = 0; j < 8; ++j) {
    double s1 = (double)a[j];
    double s2 = (double)a[j] * (double)a[j];
#pragma unroll
    for (int off = 32; off; off >>= 1) { s1 += __shfl_down(s1, off); s2 += __shfl_down(s2, off); }
    if (lane == 0) { red[wid][j][0] = s1; red[wid][j][1] = s2; }
  }
  __syncthreads();
  if (threadIdx.x < 8) {
    int j = threadIdx.x;
    double S1 = red[0][j][0] + red[1][j][0] + red[2][j][0] + red[3][j][0];
    double S2 = red[0][j][1] + red[1][j][1] + red[2][j][1] + red[3][j][1];
    atomicAdd(&stats[o0 + j], S1);
    atomicAdd(&stats[OC + o0 + j], S2);
  }
}

// ===================== BN finalize + ReLU (+optional residual), float4 (round-7 proven) =====================
template<int C>
__global__ void __launch_bounds__(256) bn_apply(const float* __restrict__ pre,
                                                const float* __restrict__ addsrc,
                                                float* __restrict__ outp,
                                                const double* __restrict__ stats,
                                                const float* __restrict__ gam,
                                                const float* __restrict__ bet,
                                                double inv_cnt) {
  __shared__ float sc[C], sh[C];
  for (int c = threadIdx.x; c < C; c += 256) {
    double mu    = stats[c] * inv_cnt;
    double var   = stats[C + c] * inv_cnt - mu * mu;
    double scale = (double)gam[c] / sqrt(var + EPSI);
    sc[c] = (float)scale;
    sh[c] = (float)((double)bet[c] - mu * scale);
  }
  __syncthreads();
  const float4* pre4 = (const float4*)pre;
  const float4* add4 = (const float4*)addsrc;
  float4* out4 = (float4*)outp;
  int total4 = NB * C * (NPT / 4);
  for (int i = blockIdx.x * 256 + threadIdx.x; i < total4; i += gridDim.x * 256) {
    int c = (i >> 9) & (C - 1);
    float s = sc[c], h = sh[c];
    float4 v = pre4[i];
    v.x = fmaxf(v.x * s + h, 0.f);
    v.y = fmaxf(v.y * s + h, 0.f);
    v.z = fmaxf(v.z * s + h, 0.f);
    v.w = fmaxf(v.w * s + h, 0.f);
    if (addsrc) {
      float4 a = add4[i];
      v.x += a.x; v.y += a.y; v.z += a.z; v.w += a.w;
    }
    out4[i] = v;
  }
}

// ===================== DSgroupMLP (round-7 proven): scrambled gather + 64x64 FC + max over k =====================
__global__ void __launch_bounds__(256) dsgroup_kernel(const float* __restrict__ x1,
                                                      const int* __restrict__ idx16,
                                                      const float* __restrict__ wf,
                                                      const float* __restrict__ bfp,
                                                      float* __restrict__ hmax,
                                                      double* __restrict__ stats) {
  __shared__ float wfT[64 * 65];
  __shared__ double dred[4][64][2];
  for (int i = threadIdx.x; i < 64 * 64; i += 256) {
    int o = i >> 6, f = i & 63;
    wfT[f * 65 + o] = wf[i];                     // i = o*64+f
  }
  __syncthreads();
  int lane = threadIdx.x & 63, wid = threadIdx.x >> 6;
  int wave = blockIdx.x * 4 + wid;
  float bo = bfp[lane];
  double s1 = 0.0, s2 = 0.0;
  for (int p = 0; p < 4; ++p) {
    int pt = wave * 4 + p;
    int b = pt >> 11, n = pt & 2047;
    int src[8];
#pragma unroll
    for (int k = 0; k < 8; ++k) {
      int j = k * NPT + n;                       // torch-view scramble: idx[(j>>3), j&7]
      src[k] = idx16[((b * NPT + (j >> 3)) << 4) | (j & 7)];
    }
    float acc[8];
#pragma unroll
    for (int k = 0; k < 8; ++k) acc[k] = bo;
    const float* x1b = x1 + b * CR * NPT;
    for (int f = 0; f < 64; ++f) {
      float wv = wfT[f * 65 + lane];             // lane = output channel o
      const float* row = x1b + f * NPT;
#pragma unroll
      for (int k = 0; k < 8; ++k) acc[k] += row[src[k]] * wv;
    }
    float hm = acc[0];
#pragma unroll
    for (int k = 0; k < 8; ++k) {
      hm = fmaxf(hm, acc[k]);
      s1 += (double)acc[k];
      s2 += (double)acc[k] * (double)acc[k];
    }
    hmax[(b * CR + lane) * NPT + n] = hm;        // max commutes with BN+ReLU (gamma>0)
  }
  dred[wid][lane][0] = s1; dred[wid][lane][1] = s2;
  __syncthreads();
  if (threadIdx.x < 64) {
    double S1 = dred[0][threadIdx.x][0] + dred[1][threadIdx.x][0] + dred[2][threadIdx.x][0] + dred[3][threadIdx.x][0];
    double S2 = dred[0][threadIdx.x][1] + dred[1][threadIdx.x][1] + dred[2][threadIdx.x][1] + dred[3][threadIdx.x][1];
    atomicAdd(&stats[threadIdx.x], S1);
    atomicAdd(&stats[64 + threadIdx.x], S2);
  }
}

// ===================== lap_fused (round-8-mega VALIDATED): BN_g inline + mean-gather + 64x64 FC =====================
__global__ void __launch_bounds__(256) lap_fused(const float* __restrict__ hpre,
                                                 const int* __restrict__ idx16,
                                                 const float* __restrict__ wl,
                                                 const float* __restrict__ blp,
                                                 float* __restrict__ tpre,
                                                 double* __restrict__ stats,
                                                 const double* __restrict__ stg,
                                                 const float* __restrict__ gg,
                                                 const float* __restrict__ bg) {
  __shared__ float wlT[64 * 65];
  __shared__ double dred[4][64][2];
  __shared__ float vstage[4][64];
  __shared__ float scg[64], shg[64];
  for (int i = threadIdx.x; i < 64 * 64; i += 256) {
    int o = i >> 6, f = i & 63;
    wlT[f * 65 + o] = wl[i];
  }
  if (threadIdx.x < 64) {
    int c = threadIdx.x;
    double mu  = stg[c] / 131072.0;
    double var = stg[64 + c] / 131072.0 - mu * mu;
    double s   = (double)gg[c] / sqrt(var + EPSI);
    scg[c] = (float)s;
    shg[c] = (float)((double)bg[c] - mu * s);
  }
  __syncthreads();
  int lane = threadIdx.x & 63, wid = threadIdx.x >> 6;
  int g = lane >> 4, cc = lane & 15;
  float blv = blp[lane];
  double s1 = 0.0, s2 = 0.0;
  for (int p = 0; p < 4; ++p) {
    int pt = (blockIdx.x * 4 + wid) * 4 + p;
    int b = pt >> 11, n = pt & 2047;
    int ch = n >> 5;                             // gathered CHANNEL is n>>5 (torch-view scramble)
    int r0 = (n & 31) << 6;
    const float* xrow = hpre + (b * CR + ch) * NPT;
    const int* ib = idx16 + ((b * NPT + r0) << 4);
    float sgc = scg[ch], shc = shg[ch];
    float msum = 0.f;
#pragma unroll
    for (int kk = 0; kk < 16; ++kk) {
      int sidx = ib[(((kk << 2) + g) << 4) | cc];
      msum += fmaxf(fmaf(xrow[sidx], sgc, shc), 0.f);    // BN_g inline
    }
    float mval = msum * 0.0625f;
    float xraw = hpre[(b * CR + lane) * NPT + n];
    float xv = fmaxf(fmaf(xraw, scg[lane], shg[lane]), 0.f);
    vstage[wid][lane] = xv - mval;
    float acc = blv;
    for (int f = 0; f < 64; ++f)
      acc += wlT[f * 65 + lane] * vstage[wid][f];
    tpre[(b * CR + lane) * NPT + n] = acc;
    s1 += (double)acc;
    s2 += (double)acc * (double)acc;
  }
  dred[wid][lane][0] = s1; dred[wid][lane][1] = s2;
  __syncthreads();
  if (threadIdx.x < 64) {
    double S1 = dred[0][threadIdx.x][0] + dred[1][threadIdx.x][0] + dred[2][threadIdx.x][0] + dred[3][threadIdx.x][0];
    double S2 = dred[0][threadIdx.x][1] + dred[1][threadIdx.x][1] + dred[2][threadIdx.x][1] + dred[3][threadIdx.x][1];
    atomicAdd(&stats[threadIdx.x], S1);
    atomicAdd(&stats[64 + threadIdx.x], S2);
  }
}

// ===================== combine (round-8-mega VALIDATED): x3 = relu(bn_g(h)) + relu(bn_l(t)), in place on h =====================
__global__ void __launch_bounds__(256) combine_kernel(float* __restrict__ hpre,
                                                      const float* __restrict__ tpre,
                                                      const double* __restrict__ stg,
                                                      const float* __restrict__ gg,
                                                      const float* __restrict__ bg,
                                                      const double* __restrict__ stl,
                                                      const float* __restrict__ gl,
                                                      const float* __restrict__ bel) {
  __shared__ float scg[64], shg[64], scl[64], shl[64];
  if (threadIdx.x < 64) {
    int c = threadIdx.x;
    double mu  = stg[c] / 131072.0;
    double var = stg[64 + c] / 131072.0 - mu * mu;
    double s   = (double)gg[c] / sqrt(var + EPSI);
    scg[c] = (float)s; shg[c] = (float)((double)bg[c] - mu * s);
    double mu2  = stl[c] / 16384.0;
    double var2 = stl[64 + c] / 16384.0 - mu2 * mu2;
    double s2   = (double)gl[c] / sqrt(var2 + EPSI);
    scl[c] = (float)s2; shl[c] = (float)((double)bel[c] - mu2 * s2);
  }
  __syncthreads();
  float4* h4 = (float4*)hpre;
  const float4* t4 = (const float4*)tpre;
  int total4 = NB * CR * (NPT / 4);
  for (int i = blockIdx.x * 256 + threadIdx.x; i < total4; i += gridDim.x * 256) {
    int c = (i >> 9) & 63;
    float sg = scg[c], hg = shg[c], sl = scl[c], hl = shl[c];
    float4 h = h4[i];
    float4 t = t4[i];
    h.x = fmaxf(h.x * sg + hg, 0.f) + fmaxf(t.x * sl + hl, 0.f);
    h.y = fmaxf(h.y * sg + hg, 0.f) + fmaxf(t.y * sl + hl, 0.f);
    h.z = fmaxf(h.z * sg + hg, 0.f) + fmaxf(t.z * sl + hl, 0.f);
    h.w = fmaxf(h.w * sg + hg, 0.f) + fmaxf(t.w * sl + hl, 0.f);
    h4[i] = h;
  }
}

// ============================ launch (11 nodes) ============================
extern "C" void kernel_launch(void* const* d_in, const int* in_sizes, int n_in,
                              void* d_out, int out_size, void* d_ws, size_t ws_size,
                              hipStream_t stream) {
  const float* xyz  = (const float*)d_in[0];
  const float* feat = (const float*)d_in[1];
  const float* w1   = (const float*)d_in[2];
  const float* b1   = (const float*)d_in[3];
  const float* g1   = (const float*)d_in[4];
  const float* be1  = (const float*)d_in[5];
  const float* wf   = (const float*)d_in[6];
  const float* bf   = (const float*)d_in[7];
  const float* gg   = (const float*)d_in[8];
  const float* bg   = (const float*)d_in[9];
  const float* wl   = (const float*)d_in[10];
  const float* bl   = (const float*)d_in[11];
  const float* gl   = (const float*)d_in[12];
  const float* bel  = (const float*)d_in[13];
  const float* w2   = (const float*)d_in[14];
  const float* b2   = (const float*)d_in[15];
  const float* g2   = (const float*)d_in[16];
  const float* be2  = (const float*)d_in[17];
  const float* w3   = (const float*)d_in[18];
  const float* b3   = (const float*)d_in[19];
  const float* g3   = (const float*)d_in[20];
  const float* be3  = (const float*)d_in[21];
  float* out = (float*)d_out;

  // d_out scratch (dead before conv3 writes out): x1, tpre, idx16
  float* x1   = out;                       // 4MB
  float* tpre = out + 1048576;             // 4MB
  int*  idx16 = (int*)(out + 2097152);     // 1MB
  // ws: hpre (hmax -> x3 in place), y2, stats (12MB + 9KB footprint, as all passing rounds)
  float*  hpre  = (float*)d_ws;            // 4MB
  float*  y2    = hpre + 1048576;          // 8MB
  double* stats = (double*)((char*)d_ws + (12u << 20));
  double* st0 = stats;        // 128
  double* stg = stats + 128;  // 128
  double* stl = stats + 256;  // 128
  double* st2 = stats + 384;  // 256
  double* st3 = stats + 640;  // 512

  hipMemsetAsync(stats, 0, 1152 * sizeof(double), stream);

  // 1: kNN (separate dispatch — exact round-6/7 context)
  knn_kernel<<<4096, 256, 0, stream>>>(xyz, idx16);
  // 2: conv1 -> x1 + st0 (exact round-7 context)
  conv_stats<128, 64><<<512, 256, 0, stream>>>(feat, w1, b1, x1, st0);
  // 3: bn1 -> x1 in place
  bn_apply<64><<<1024, 256, 0, stream>>>(x1, nullptr, x1, st0, g1, be1, 1.0 / 16384.0);
  // 4: dsgroup -> hpre (pre-BN max) + stg
  dsgroup_kernel<<<1024, 256, 0, stream>>>(x1, idx16, wf, bf, hpre, stg);
  // 5: lap (BN_g inline) -> tpre + stl
  lap_fused<<<1024, 256, 0, stream>>>(hpre, idx16, wl, bl, tpre, stl, stg, gg, bg);
  // 6: combine -> x3 in hpre
  combine_kernel<<<1024, 256, 0, stream>>>(hpre, tpre, stg, gg, bg, stl, gl, bel);
  // 7: conv2 -> y2 + st2
  conv_stats<64, 128><<<1024, 256, 0, stream>>>(hpre, w2, b2, y2, st2);
  // 8: bn2 + feat residual -> y2 in place
  bn_apply<128><<<1024, 256, 0, stream>>>(y2, feat, y2, st2, g2, be2, 1.0 / 16384.0);
  // 9: conv3 -> out + st3
  conv_stats<128, 256><<<2048, 256, 0, stream>>>(y2, w3, b3, out, st3);
  // 10: bn3 -> out in place
  bn_apply<256><<<1024, 256, 0, stream>>>(out, nullptr, out, st3, g3, be3, 1.0 / 16384.0);
}